// Round 4
// baseline (136.100 us; speedup 1.0000x reference)
//
#include <hip/hip_runtime.h>
#include <stdint.h>

#define NN 6144
#define NUSER 4096
#define RR 2
#define KK 3
#define FIN 25
#define FOUT 64
#define DD2 64
#define CAP 192

__device__ __forceinline__ float wave_reduce_sum(float v) {
    #pragma unroll
    for (int off = 32; off >= 1; off >>= 1) v += __shfl_xor(v, off);
    return v;
}
__device__ __forceinline__ float wave_reduce_max(float v) {
    #pragma unroll
    for (int off = 32; off >= 1; off >>= 1) v = fmaxf(v, __shfl_xor(v, off));
    return v;
}
__device__ __forceinline__ unsigned short f2bf(float x) {   // RNE
    unsigned int u = __float_as_uint(x);
    unsigned int r = (u + 0x7fffu + ((u >> 16) & 1u)) >> 16;
    return (unsigned short)r;
}
__device__ __forceinline__ float bf2f(unsigned short b) {
    return __uint_as_float(((unsigned int)b) << 16);
}

// One wave per (r,n): hp for all 3 heads (packed bf16 ushort4) + s,d float4.
__global__ __launch_bounds__(128) void k1_proj(
    const float* __restrict__ h, const float* __restrict__ w,
    const float* __restrict__ asrc, const float* __restrict__ adst,
    ushort4* __restrict__ hpq, float4* __restrict__ sq, float4* __restrict__ dq)
{
    const int wid  = threadIdx.x >> 6;
    const int lane = threadIdx.x & 63;
    const int row  = blockIdx.x * 2 + wid;     // r*NN + n
    const int r    = row / NN;
    const int n    = row % NN;

    const float* hrow = h + (size_t)n * FIN;
    float acc[KK];
    #pragma unroll
    for (int k = 0; k < KK; ++k) {
        const float* wp = w + ((size_t)(r * KK + k) * FIN) * FOUT + lane;
        float a = 0.f;
        #pragma unroll
        for (int f = 0; f < FIN; ++f) a += hrow[f] * wp[f * FOUT];
        acc[k] = a;
    }

    ushort4 pk;
    pk.x = f2bf(acc[0]); pk.y = f2bf(acc[1]); pk.z = f2bf(acc[2]); pk.w = 0;
    hpq[(size_t)row * FOUT + lane] = pk;

    float sv0 = wave_reduce_sum(acc[0] * asrc[(r * KK + 0) * FOUT + lane]);
    float sv1 = wave_reduce_sum(acc[1] * asrc[(r * KK + 1) * FOUT + lane]);
    float sv2 = wave_reduce_sum(acc[2] * asrc[(r * KK + 2) * FOUT + lane]);
    float dv0 = wave_reduce_sum(acc[0] * adst[(r * KK + 0) * FOUT + lane]);
    float dv1 = wave_reduce_sum(acc[1] * adst[(r * KK + 1) * FOUT + lane]);
    float dv2 = wave_reduce_sum(acc[2] * adst[(r * KK + 2) * FOUT + lane]);
    if (lane == 0) {
        sq[row] = make_float4(sv0, sv1, sv2, 0.f);
        dq[row] = make_float4(dv0, dv1, dv2, 0.f);
    }
}

// One 256-thread block per (r,n) row: 4-wave ballot-compaction scan,
// block-level fused 3-head softmax, 4-way-split packed-bf16 PV gather.
__global__ __launch_bounds__(256) void k2_gat(
    const int* __restrict__ hadj, const ushort4* __restrict__ hpq,
    const float4* __restrict__ sq, const float4* __restrict__ dq,
    const float* __restrict__ bias, float* __restrict__ embs)
{
    const int row  = blockIdx.x;               // r*NN + n
    const int r    = row / NN;
    const int tid  = threadIdx.x;
    const int wid  = tid >> 6;
    const int lane = tid & 63;

    __shared__ int   nbr[CAP];
    __shared__ float pw[3][CAP];
    __shared__ float redm[3][4], reds[3][4];
    __shared__ float acc_s[3][4][FOUT];
    __shared__ int   cnt;

    if (tid == 0) cnt = 0;
    __syncthreads();

    // ---- scan: wave wid covers ints [wid*1536, wid*1536+1536), 6 iters x int4
    const int* rowp = hadj + (size_t)row * NN;
    const unsigned long long below = (1ull << lane) - 1ull;
    #pragma unroll
    for (int t = 0; t < 6; ++t) {
        const int m0 = wid * 1536 + t * 256 + lane * 4;
        const int4 v = *reinterpret_cast<const int4*>(rowp + m0);
        const unsigned long long b0 = __ballot(v.x != 0);
        const unsigned long long b1 = __ballot(v.y != 0);
        const unsigned long long b2 = __ballot(v.z != 0);
        const unsigned long long b3 = __ballot(v.w != 0);
        const int n0 = __popcll(b0), n1 = __popcll(b1);
        const int n2 = __popcll(b2), n3 = __popcll(b3);
        const int tot = n0 + n1 + n2 + n3;
        int base = 0;
        if (tot) {
            if (lane == 0) base = atomicAdd(&cnt, tot);
            base = __shfl(base, 0);
            const int o0 = base + __popcll(b0 & below);
            const int o1 = base + n0 + __popcll(b1 & below);
            const int o2 = base + n0 + n1 + __popcll(b2 & below);
            const int o3 = base + n0 + n1 + n2 + __popcll(b3 & below);
            if (v.x && o0 < CAP) nbr[o0] = m0 + 0;
            if (v.y && o1 < CAP) nbr[o1] = m0 + 1;
            if (v.z && o2 < CAP) nbr[o2] = m0 + 2;
            if (v.w && o3 < CAP) nbr[o3] = m0 + 3;
        }
    }
    __syncthreads();
    const int count = cnt > CAP ? CAP : cnt;

    // ---- fused 3-head logits (one float4 d-gather per neighbor, 256-wide)
    const float4 sv = sq[row];
    const float4* dqr = dq + (size_t)r * NN;
    float mx0 = -1e30f, mx1 = -1e30f, mx2 = -1e30f;
    for (int j = tid; j < count; j += 256) {
        const float4 dv = dqr[nbr[j]];
        float e0 = sv.x + dv.x; e0 = (e0 >= 0.f) ? e0 : 0.2f * e0;
        float e1 = sv.y + dv.y; e1 = (e1 >= 0.f) ? e1 : 0.2f * e1;
        float e2 = sv.z + dv.z; e2 = (e2 >= 0.f) ? e2 : 0.2f * e2;
        pw[0][j] = e0; pw[1][j] = e1; pw[2][j] = e2;
        mx0 = fmaxf(mx0, e0); mx1 = fmaxf(mx1, e1); mx2 = fmaxf(mx2, e2);
    }
    mx0 = wave_reduce_max(mx0);
    mx1 = wave_reduce_max(mx1);
    mx2 = wave_reduce_max(mx2);
    if (lane == 0) { redm[0][wid] = mx0; redm[1][wid] = mx1; redm[2][wid] = mx2; }
    __syncthreads();
    mx0 = fmaxf(fmaxf(redm[0][0], redm[0][1]), fmaxf(redm[0][2], redm[0][3]));
    mx1 = fmaxf(fmaxf(redm[1][0], redm[1][1]), fmaxf(redm[1][2], redm[1][3]));
    mx2 = fmaxf(fmaxf(redm[2][0], redm[2][1]), fmaxf(redm[2][2], redm[2][3]));

    float ss0 = 0.f, ss1 = 0.f, ss2 = 0.f;
    for (int j = tid; j < count; j += 256) {   // same j-set each thread wrote
        float p0 = __expf(pw[0][j] - mx0); pw[0][j] = p0; ss0 += p0;
        float p1 = __expf(pw[1][j] - mx1); pw[1][j] = p1; ss1 += p1;
        float p2 = __expf(pw[2][j] - mx2); pw[2][j] = p2; ss2 += p2;
    }
    ss0 = wave_reduce_sum(ss0);
    ss1 = wave_reduce_sum(ss1);
    ss2 = wave_reduce_sum(ss2);
    if (lane == 0) { reds[0][wid] = ss0; reds[1][wid] = ss1; reds[2][wid] = ss2; }
    __syncthreads();
    ss0 = reds[0][0] + reds[0][1] + reds[0][2] + reds[0][3];
    ss1 = reds[1][0] + reds[1][1] + reds[1][2] + reds[1][3];
    ss2 = reds[2][0] + reds[2][1] + reds[2][2] + reds[2][3];

    // ---- PV gather: wave wid takes j = wid, wid+4, ... (coalesced 512B/load)
    const ushort4* hq = hpq + ((size_t)r * NN) * FOUT + lane;
    float a0 = 0.f, a1 = 0.f, a2 = 0.f;
    for (int j = wid; j < count; j += 4) {
        const ushort4 v = hq[(size_t)nbr[j] * FOUT];
        a0 += pw[0][j] * bf2f(v.x);
        a1 += pw[1][j] * bf2f(v.y);
        a2 += pw[2][j] * bf2f(v.z);
    }
    acc_s[0][wid][lane] = a0;
    acc_s[1][wid][lane] = a1;
    acc_s[2][wid][lane] = a2;
    __syncthreads();
    if (wid == 0) {
        const float t0 = acc_s[0][0][lane] + acc_s[0][1][lane] + acc_s[0][2][lane] + acc_s[0][3][lane];
        const float t1 = acc_s[1][0][lane] + acc_s[1][1][lane] + acc_s[1][2][lane] + acc_s[1][3][lane];
        const float t2 = acc_s[2][0][lane] + acc_s[2][1][lane] + acc_s[2][2][lane] + acc_s[2][3][lane];
        const float tot = t0 / ss0 + t1 / ss1 + t2 / ss2;
        embs[(size_t)row * FOUT + lane] = tot * (1.f / 3.f) + bias[r * FOUT + lane];
    }
}

// One wave per user node: semantic attention fusion + classifier + log_softmax.
__global__ __launch_bounds__(64) void k3_fuse(
    const float* __restrict__ h, const float* __restrict__ embs,
    const float* __restrict__ aw1, const float* __restrict__ aw2,
    const float* __restrict__ am, const float* __restrict__ fcw,
    const float* __restrict__ fcb, float* __restrict__ out)
{
    const int n = blockIdx.x;
    const int o = threadIdx.x;

    __shared__ float sh[2][FOUT];
    const float ta0 = embs[((size_t)0 * NN + n) * FOUT + o];
    const float ta1 = embs[((size_t)1 * NN + n) * FOUT + o];
    sh[0][o] = ta0;
    sh[1][o] = ta1;

    float fa = 0.f;
    const float* hrow = h + (size_t)n * FIN;
    #pragma unroll
    for (int f = 0; f < FIN; ++f) fa += hrow[f] * aw1[f * DD2 + o];
    __syncthreads();

    float e[2];
    #pragma unroll
    for (int r = 0; r < 2; ++r) {
        float t = fa;
        #pragma unroll 8
        for (int j = 0; j < FOUT; ++j) t += sh[r][j] * aw2[j * DD2 + o];
        float q = tanhf(t);
        e[r] = wave_reduce_sum(q * am[o]);
    }
    const float mx = fmaxf(e[0], e[1]);
    float b0 = __expf(e[0] - mx), b1 = __expf(e[1] - mx);
    const float inv = 1.f / (b0 + b1);
    b0 *= inv; b1 *= inv;
    const float fus = b0 * ta0 + b1 * ta1;

    float p0 = ta0 * fcw[(o      ) * 2 + 0] + ta1 * fcw[(64 + o) * 2 + 0] + fus * fcw[(128 + o) * 2 + 0];
    float p1 = ta0 * fcw[(o      ) * 2 + 1] + ta1 * fcw[(64 + o) * 2 + 1] + fus * fcw[(128 + o) * 2 + 1];
    const float lg0 = wave_reduce_sum(p0) + fcb[0];
    const float lg1 = wave_reduce_sum(p1) + fcb[1];

    if (o == 0) {
        const float m2  = fmaxf(lg0, lg1);
        const float lse = m2 + logf(__expf(lg0 - m2) + __expf(lg1 - m2));
        out[(size_t)n * 2 + 0] = lg0 - lse;
        out[(size_t)n * 2 + 1] = lg1 - lse;
    }
}

extern "C" void kernel_launch(void* const* d_in, const int* in_sizes, int n_in,
                              void* d_out, int out_size, void* d_ws, size_t ws_size,
                              hipStream_t stream)
{
    const int*   hadj = (const int*)d_in[0];
    const float* h    = (const float*)d_in[1];
    const float* w    = (const float*)d_in[2];
    const float* asrc = (const float*)d_in[3];
    const float* adst = (const float*)d_in[4];
    const float* bias = (const float*)d_in[5];
    const float* aw1  = (const float*)d_in[6];
    const float* aw2  = (const float*)d_in[7];
    const float* am   = (const float*)d_in[8];
    const float* fcw  = (const float*)d_in[9];
    const float* fcb  = (const float*)d_in[10];
    float* out = (float*)d_out;

    char* ws = (char*)d_ws;
    ushort4* hpq = (ushort4*)ws;                       // RR*NN*64*8 B = 6.29 MB
    ws += (size_t)RR * NN * FOUT * sizeof(ushort4);
    float4* sq = (float4*)ws;                          // RR*NN*16 B
    ws += (size_t)RR * NN * sizeof(float4);
    float4* dq = (float4*)ws;                          // RR*NN*16 B
    ws += (size_t)RR * NN * sizeof(float4);
    float* embs = (float*)ws;                          // RR*NN*64*4 B

    k1_proj<<<RR * NN / 2, 128, 0, stream>>>(h, w, asrc, adst, hpq, sq, dq);
    k2_gat <<<RR * NN,     256, 0, stream>>>(hadj, hpq, sq, dq, bias, embs);
    k3_fuse<<<NUSER, 64, 0, stream>>>(h, embs, aw1, aw2, am, fcw, fcb, out);
}

// Round 6
// 117.816 us; speedup vs baseline: 1.1552x; 1.1552x over previous
//
#include <hip/hip_runtime.h>
#include <stdint.h>

#define NN 6144
#define NUSER 4096
#define RR 2
#define KK 3
#define FIN 25
#define FOUT 64
#define DD2 64
#define CAP 192

typedef int int4v __attribute__((ext_vector_type(4)));

__device__ __forceinline__ float wave_reduce_sum(float v) {
    #pragma unroll
    for (int off = 32; off >= 1; off >>= 1) v += __shfl_xor(v, off);
    return v;
}
__device__ __forceinline__ float wave_reduce_max(float v) {
    #pragma unroll
    for (int off = 32; off >= 1; off >>= 1) v = fmaxf(v, __shfl_xor(v, off));
    return v;
}
__device__ __forceinline__ unsigned short f2bf(float x) {   // RNE
    unsigned int u = __float_as_uint(x);
    unsigned int r = (u + 0x7fffu + ((u >> 16) & 1u)) >> 16;
    return (unsigned short)r;
}
__device__ __forceinline__ float bf2f(unsigned short b) {
    return __uint_as_float(((unsigned int)b) << 16);
}

// ---- kA: pure streaming CSR build. One wave per (r,n) row. No LDS, no
// barriers, no atomics -> max occupancy, scan at streaming BW.
__global__ __launch_bounds__(256) void kA_csr(
    const int* __restrict__ hadj, int* __restrict__ cnt, int* __restrict__ idx)
{
    const int gwave = (blockIdx.x * 256 + threadIdx.x) >> 6;   // row id
    const int lane  = threadIdx.x & 63;
    const int* rowp   = hadj + (size_t)gwave * NN;
    int*       rowidx = idx  + (size_t)gwave * CAP;
    const unsigned long long below = (1ull << lane) - 1ull;

    int base = 0;
    #pragma unroll 4
    for (int t = 0; t < 24; ++t) {
        const int m0 = t * 256 + lane * 4;
        const int4v v = __builtin_nontemporal_load(
            reinterpret_cast<const int4v*>(rowp + m0));
        const unsigned long long b0 = __ballot(v.x != 0);
        const unsigned long long b1 = __ballot(v.y != 0);
        const unsigned long long b2 = __ballot(v.z != 0);
        const unsigned long long b3 = __ballot(v.w != 0);
        const int n0 = __popcll(b0), n1 = __popcll(b1);
        const int n2 = __popcll(b2), n3 = __popcll(b3);
        const int o0 = base + __popcll(b0 & below);
        const int o1 = base + n0 + __popcll(b1 & below);
        const int o2 = base + n0 + n1 + __popcll(b2 & below);
        const int o3 = base + n0 + n1 + n2 + __popcll(b3 & below);
        if (v.x && o0 < CAP) rowidx[o0] = m0 + 0;
        if (v.y && o1 < CAP) rowidx[o1] = m0 + 1;
        if (v.z && o2 < CAP) rowidx[o2] = m0 + 2;
        if (v.w && o3 < CAP) rowidx[o3] = m0 + 3;
        base += n0 + n1 + n2 + n3;
    }
    if (lane == 0) cnt[gwave] = base > CAP ? CAP : base;
}

// ---- k1: one wave per (r,n): hp all 3 heads (packed bf16 ushort4) + s,d.
__global__ __launch_bounds__(128) void k1_proj(
    const float* __restrict__ h, const float* __restrict__ w,
    const float* __restrict__ asrc, const float* __restrict__ adst,
    ushort4* __restrict__ hpq, float4* __restrict__ sq, float4* __restrict__ dq)
{
    const int wid  = threadIdx.x >> 6;
    const int lane = threadIdx.x & 63;
    const int row  = blockIdx.x * 2 + wid;     // r*NN + n
    const int r    = row / NN;
    const int n    = row % NN;

    const float* hrow = h + (size_t)n * FIN;
    float acc[KK];
    #pragma unroll
    for (int k = 0; k < KK; ++k) {
        const float* wp = w + ((size_t)(r * KK + k) * FIN) * FOUT + lane;
        float a = 0.f;
        #pragma unroll
        for (int f = 0; f < FIN; ++f) a += hrow[f] * wp[f * FOUT];
        acc[k] = a;
    }

    ushort4 pk;
    pk.x = f2bf(acc[0]); pk.y = f2bf(acc[1]); pk.z = f2bf(acc[2]); pk.w = 0;
    hpq[(size_t)row * FOUT + lane] = pk;

    float sv0 = wave_reduce_sum(acc[0] * asrc[(r * KK + 0) * FOUT + lane]);
    float sv1 = wave_reduce_sum(acc[1] * asrc[(r * KK + 1) * FOUT + lane]);
    float sv2 = wave_reduce_sum(acc[2] * asrc[(r * KK + 2) * FOUT + lane]);
    float dv0 = wave_reduce_sum(acc[0] * adst[(r * KK + 0) * FOUT + lane]);
    float dv1 = wave_reduce_sum(acc[1] * adst[(r * KK + 1) * FOUT + lane]);
    float dv2 = wave_reduce_sum(acc[2] * adst[(r * KK + 2) * FOUT + lane]);
    if (lane == 0) {
        sq[row] = make_float4(sv0, sv1, sv2, 0.f);
        dq[row] = make_float4(dv0, dv1, dv2, 0.f);
    }
}

// ---- kB: one wave per (r,n) row from CSR; fused 3-head softmax + PV gather.
// 4 waves/block, each wave owns its LDS slice: NO barriers.
__global__ __launch_bounds__(256) void kB_gat(
    const int* __restrict__ cnt, const int* __restrict__ idx,
    const ushort4* __restrict__ hpq, const float4* __restrict__ sq,
    const float4* __restrict__ dq, const float* __restrict__ bias,
    float* __restrict__ embs)
{
    const int wid  = threadIdx.x >> 6;
    const int lane = threadIdx.x & 63;
    const int row  = blockIdx.x * 4 + wid;     // r*NN + n
    const int r    = row / NN;

    __shared__ int   nbr_s[4][CAP];
    __shared__ float pw_s[4][3][CAP];
    int* nbr = nbr_s[wid];
    float (*pw)[CAP] = pw_s[wid];

    const int count = cnt[row];
    const int* rowidx = idx + (size_t)row * CAP;

    // logits for all 3 heads (one float4 d-gather per neighbor)
    const float4 sv = sq[row];
    const float4* dqr = dq + (size_t)r * NN;
    float mx0 = -1e30f, mx1 = -1e30f, mx2 = -1e30f;
    for (int j = lane; j < count; j += 64) {
        const int nb = rowidx[j];
        nbr[j] = nb;
        const float4 dv = dqr[nb];
        float e0 = sv.x + dv.x; e0 = (e0 >= 0.f) ? e0 : 0.2f * e0;
        float e1 = sv.y + dv.y; e1 = (e1 >= 0.f) ? e1 : 0.2f * e1;
        float e2 = sv.z + dv.z; e2 = (e2 >= 0.f) ? e2 : 0.2f * e2;
        pw[0][j] = e0; pw[1][j] = e1; pw[2][j] = e2;
        mx0 = fmaxf(mx0, e0); mx1 = fmaxf(mx1, e1); mx2 = fmaxf(mx2, e2);
    }
    mx0 = wave_reduce_max(mx0);
    mx1 = wave_reduce_max(mx1);
    mx2 = wave_reduce_max(mx2);

    float ss0 = 0.f, ss1 = 0.f, ss2 = 0.f;
    for (int j = lane; j < count; j += 64) {
        float p0 = __expf(pw[0][j] - mx0); pw[0][j] = p0; ss0 += p0;
        float p1 = __expf(pw[1][j] - mx1); pw[1][j] = p1; ss1 += p1;
        float p2 = __expf(pw[2][j] - mx2); pw[2][j] = p2; ss2 += p2;
    }
    ss0 = wave_reduce_sum(ss0);
    ss1 = wave_reduce_sum(ss1);
    ss2 = wave_reduce_sum(ss2);

    // PV gather: one ushort4 (3 heads bf16) coalesced load per neighbor
    const ushort4* hq = hpq + ((size_t)r * NN) * FOUT + lane;
    float a0 = 0.f, a1 = 0.f, a2 = 0.f;
    int j = 0;
    for (; j + 4 <= count; j += 4) {
        #pragma unroll
        for (int u = 0; u < 4; ++u) {
            const ushort4 v = hq[(size_t)nbr[j + u] * FOUT];
            a0 += pw[0][j + u] * bf2f(v.x);
            a1 += pw[1][j + u] * bf2f(v.y);
            a2 += pw[2][j + u] * bf2f(v.z);
        }
    }
    for (; j < count; ++j) {
        const ushort4 v = hq[(size_t)nbr[j] * FOUT];
        a0 += pw[0][j] * bf2f(v.x);
        a1 += pw[1][j] * bf2f(v.y);
        a2 += pw[2][j] * bf2f(v.z);
    }

    const float tot = a0 / ss0 + a1 / ss1 + a2 / ss2;
    embs[(size_t)row * FOUT + lane] = tot * (1.f / 3.f) + bias[r * FOUT + lane];
}

// ---- k3: one wave per user node: semantic fusion + classifier + log_softmax.
__global__ __launch_bounds__(64) void k3_fuse(
    const float* __restrict__ h, const float* __restrict__ embs,
    const float* __restrict__ aw1, const float* __restrict__ aw2,
    const float* __restrict__ am, const float* __restrict__ fcw,
    const float* __restrict__ fcb, float* __restrict__ out)
{
    const int n = blockIdx.x;
    const int o = threadIdx.x;

    __shared__ float sh[2][FOUT];
    const float ta0 = embs[((size_t)0 * NN + n) * FOUT + o];
    const float ta1 = embs[((size_t)1 * NN + n) * FOUT + o];
    sh[0][o] = ta0;
    sh[1][o] = ta1;

    float fa = 0.f;
    const float* hrow = h + (size_t)n * FIN;
    #pragma unroll
    for (int f = 0; f < FIN; ++f) fa += hrow[f] * aw1[f * DD2 + o];
    __syncthreads();

    float e[2];
    #pragma unroll
    for (int r = 0; r < 2; ++r) {
        float t = fa;
        #pragma unroll 8
        for (int j = 0; j < FOUT; ++j) t += sh[r][j] * aw2[j * DD2 + o];
        float q = tanhf(t);
        e[r] = wave_reduce_sum(q * am[o]);
    }
    const float mx = fmaxf(e[0], e[1]);
    float b0 = __expf(e[0] - mx), b1 = __expf(e[1] - mx);
    const float inv = 1.f / (b0 + b1);
    b0 *= inv; b1 *= inv;
    const float fus = b0 * ta0 + b1 * ta1;

    float p0 = ta0 * fcw[(o      ) * 2 + 0] + ta1 * fcw[(64 + o) * 2 + 0] + fus * fcw[(128 + o) * 2 + 0];
    float p1 = ta0 * fcw[(o      ) * 2 + 1] + ta1 * fcw[(64 + o) * 2 + 1] + fus * fcw[(128 + o) * 2 + 1];
    const float lg0 = wave_reduce_sum(p0) + fcb[0];
    const float lg1 = wave_reduce_sum(p1) + fcb[1];

    if (o == 0) {
        const float m2  = fmaxf(lg0, lg1);
        const float lse = m2 + logf(__expf(lg0 - m2) + __expf(lg1 - m2));
        out[(size_t)n * 2 + 0] = lg0 - lse;
        out[(size_t)n * 2 + 1] = lg1 - lse;
    }
}

extern "C" void kernel_launch(void* const* d_in, const int* in_sizes, int n_in,
                              void* d_out, int out_size, void* d_ws, size_t ws_size,
                              hipStream_t stream)
{
    const int*   hadj = (const int*)d_in[0];
    const float* h    = (const float*)d_in[1];
    const float* w    = (const float*)d_in[2];
    const float* asrc = (const float*)d_in[3];
    const float* adst = (const float*)d_in[4];
    const float* bias = (const float*)d_in[5];
    const float* aw1  = (const float*)d_in[6];
    const float* aw2  = (const float*)d_in[7];
    const float* am   = (const float*)d_in[8];
    const float* fcw  = (const float*)d_in[9];
    const float* fcb  = (const float*)d_in[10];
    float* out = (float*)d_out;

    char* ws = (char*)d_ws;
    ushort4* hpq = (ushort4*)ws;                       // RR*NN*64*8 B = 6.29 MB
    ws += (size_t)RR * NN * FOUT * sizeof(ushort4);
    float4* sq = (float4*)ws;                          // RR*NN*16 B
    ws += (size_t)RR * NN * sizeof(float4);
    float4* dq = (float4*)ws;                          // RR*NN*16 B
    ws += (size_t)RR * NN * sizeof(float4);
    float* embs = (float*)ws;                          // RR*NN*64*4 B
    ws += (size_t)RR * NN * FOUT * sizeof(float);
    int* cnt = (int*)ws;                               // RR*NN*4 B
    ws += (size_t)RR * NN * sizeof(int);
    int* idx = (int*)ws;                               // RR*NN*CAP*4 B = 9.4 MB

    kA_csr <<<RR * NN / 4, 256, 0, stream>>>(hadj, cnt, idx);
    k1_proj<<<RR * NN / 2, 128, 0, stream>>>(h, w, asrc, adst, hpq, sq, dq);
    kB_gat <<<RR * NN / 4, 256, 0, stream>>>(cnt, idx, hpq, sq, dq, bias, embs);
    k3_fuse<<<NUSER, 64, 0, stream>>>(h, embs, aw1, aw2, am, fcw, fcb, out);
}

// Round 7
// 91.989 us; speedup vs baseline: 1.4795x; 1.2808x over previous
//
#include <hip/hip_runtime.h>
#include <stdint.h>

#define NN 6144
#define NUSER 4096
#define RR 2
#define KK 3
#define FIN 25
#define FOUT 64
#define DD2 64
#define CAP 192

typedef int int4v __attribute__((ext_vector_type(4)));

__device__ __forceinline__ float wave_reduce_sum(float v) {
    #pragma unroll
    for (int off = 32; off >= 1; off >>= 1) v += __shfl_xor(v, off);
    return v;
}
__device__ __forceinline__ float wave_reduce_max(float v) {
    #pragma unroll
    for (int off = 32; off >= 1; off >>= 1) v = fmaxf(v, __shfl_xor(v, off));
    return v;
}
__device__ __forceinline__ unsigned short f2bf(float x) {   // RNE
    unsigned int u = __float_as_uint(x);
    unsigned int r = (u + 0x7fffu + ((u >> 16) & 1u)) >> 16;
    return (unsigned short)r;
}
__device__ __forceinline__ float bf2f(unsigned short b) {
    return __uint_as_float(((unsigned int)b) << 16);
}

// ---- kA: streaming CSR build, ONLY user rows (n < NUSER) per relation.
// One wave per row, no LDS/barriers/atomics.
__global__ __launch_bounds__(256) void kA_csr(
    const int* __restrict__ hadj, int* __restrict__ cnt, int* __restrict__ idx)
{
    const int urow = (blockIdx.x * 256 + threadIdx.x) >> 6;  // r*NUSER + n
    const int lane = threadIdx.x & 63;
    const int r    = urow / NUSER;
    const int n    = urow - r * NUSER;
    const int* rowp   = hadj + ((size_t)r * NN + n) * NN;
    int*       rowidx = idx  + (size_t)urow * CAP;
    const unsigned long long below = (1ull << lane) - 1ull;

    int base = 0;
    #pragma unroll 4
    for (int t = 0; t < 24; ++t) {
        const int m0 = t * 256 + lane * 4;
        const int4v v = __builtin_nontemporal_load(
            reinterpret_cast<const int4v*>(rowp + m0));
        const unsigned long long b0 = __ballot(v.x != 0);
        const unsigned long long b1 = __ballot(v.y != 0);
        const unsigned long long b2 = __ballot(v.z != 0);
        const unsigned long long b3 = __ballot(v.w != 0);
        const int n0 = __popcll(b0), n1 = __popcll(b1);
        const int n2 = __popcll(b2), n3 = __popcll(b3);
        const int o0 = base + __popcll(b0 & below);
        const int o1 = base + n0 + __popcll(b1 & below);
        const int o2 = base + n0 + n1 + __popcll(b2 & below);
        const int o3 = base + n0 + n1 + n2 + __popcll(b3 & below);
        if (v.x && o0 < CAP) rowidx[o0] = m0 + 0;
        if (v.y && o1 < CAP) rowidx[o1] = m0 + 1;
        if (v.z && o2 < CAP) rowidx[o2] = m0 + 2;
        if (v.w && o3 < CAP) rowidx[o3] = m0 + 3;
        base += n0 + n1 + n2 + n3;
    }
    if (lane == 0) cnt[urow] = base > CAP ? CAP : base;
}

// ---- k1: one wave per (r,n), ALL n: hp 3 heads (packed bf16) + s,d.
__global__ __launch_bounds__(128) void k1_proj(
    const float* __restrict__ h, const float* __restrict__ w,
    const float* __restrict__ asrc, const float* __restrict__ adst,
    ushort4* __restrict__ hpq, float4* __restrict__ sq, float4* __restrict__ dq)
{
    const int wid  = threadIdx.x >> 6;
    const int lane = threadIdx.x & 63;
    const int row  = blockIdx.x * 2 + wid;     // r*NN + n
    const int r    = row / NN;
    const int n    = row % NN;

    const float* hrow = h + (size_t)n * FIN;
    float acc[KK];
    #pragma unroll
    for (int k = 0; k < KK; ++k) {
        const float* wp = w + ((size_t)(r * KK + k) * FIN) * FOUT + lane;
        float a = 0.f;
        #pragma unroll
        for (int f = 0; f < FIN; ++f) a += hrow[f] * wp[f * FOUT];
        acc[k] = a;
    }

    ushort4 pk;
    pk.x = f2bf(acc[0]); pk.y = f2bf(acc[1]); pk.z = f2bf(acc[2]); pk.w = 0;
    hpq[(size_t)row * FOUT + lane] = pk;

    float sv0 = wave_reduce_sum(acc[0] * asrc[(r * KK + 0) * FOUT + lane]);
    float sv1 = wave_reduce_sum(acc[1] * asrc[(r * KK + 1) * FOUT + lane]);
    float sv2 = wave_reduce_sum(acc[2] * asrc[(r * KK + 2) * FOUT + lane]);
    float dv0 = wave_reduce_sum(acc[0] * adst[(r * KK + 0) * FOUT + lane]);
    float dv1 = wave_reduce_sum(acc[1] * adst[(r * KK + 1) * FOUT + lane]);
    float dv2 = wave_reduce_sum(acc[2] * adst[(r * KK + 2) * FOUT + lane]);
    if (lane == 0) {
        sq[row] = make_float4(sv0, sv1, sv2, 0.f);
        dq[row] = make_float4(dv0, dv1, dv2, 0.f);
    }
}

// ---- kB: one wave per user row from CSR; fused 3-head softmax + PV gather.
// 4 waves/block, each wave owns its LDS slice: no barriers.
__global__ __launch_bounds__(256) void kB_gat(
    const int* __restrict__ cnt, const int* __restrict__ idx,
    const ushort4* __restrict__ hpq, const float4* __restrict__ sq,
    const float4* __restrict__ dq, const float* __restrict__ bias,
    float* __restrict__ embs)
{
    const int wid  = threadIdx.x >> 6;
    const int lane = threadIdx.x & 63;
    const int urow = blockIdx.x * 4 + wid;     // r*NUSER + n
    const int r    = urow / NUSER;
    const int n    = urow - r * NUSER;

    __shared__ int   nbr_s[4][CAP];
    __shared__ float pw_s[4][3][CAP];
    int* nbr = nbr_s[wid];
    float (*pw)[CAP] = pw_s[wid];

    const int count = cnt[urow];
    const int* rowidx = idx + (size_t)urow * CAP;

    // logits for all 3 heads (one float4 d-gather per neighbor)
    const float4 sv = sq[(size_t)r * NN + n];
    const float4* dqr = dq + (size_t)r * NN;
    float mx0 = -1e30f, mx1 = -1e30f, mx2 = -1e30f;
    for (int j = lane; j < count; j += 64) {
        const int nb = rowidx[j];
        nbr[j] = nb;
        const float4 dv = dqr[nb];
        float e0 = sv.x + dv.x; e0 = (e0 >= 0.f) ? e0 : 0.2f * e0;
        float e1 = sv.y + dv.y; e1 = (e1 >= 0.f) ? e1 : 0.2f * e1;
        float e2 = sv.z + dv.z; e2 = (e2 >= 0.f) ? e2 : 0.2f * e2;
        pw[0][j] = e0; pw[1][j] = e1; pw[2][j] = e2;
        mx0 = fmaxf(mx0, e0); mx1 = fmaxf(mx1, e1); mx2 = fmaxf(mx2, e2);
    }
    mx0 = wave_reduce_max(mx0);
    mx1 = wave_reduce_max(mx1);
    mx2 = wave_reduce_max(mx2);

    float ss0 = 0.f, ss1 = 0.f, ss2 = 0.f;
    for (int j = lane; j < count; j += 64) {
        float p0 = __expf(pw[0][j] - mx0); pw[0][j] = p0; ss0 += p0;
        float p1 = __expf(pw[1][j] - mx1); pw[1][j] = p1; ss1 += p1;
        float p2 = __expf(pw[2][j] - mx2); pw[2][j] = p2; ss2 += p2;
    }
    ss0 = wave_reduce_sum(ss0);
    ss1 = wave_reduce_sum(ss1);
    ss2 = wave_reduce_sum(ss2);

    // PV gather: one ushort4 (3 heads bf16) coalesced load per neighbor
    const ushort4* hq = hpq + ((size_t)r * NN) * FOUT + lane;
    float a0 = 0.f, a1 = 0.f, a2 = 0.f;
    int j = 0;
    for (; j + 4 <= count; j += 4) {
        #pragma unroll
        for (int u = 0; u < 4; ++u) {
            const ushort4 v = hq[(size_t)nbr[j + u] * FOUT];
            a0 += pw[0][j + u] * bf2f(v.x);
            a1 += pw[1][j + u] * bf2f(v.y);
            a2 += pw[2][j + u] * bf2f(v.z);
        }
    }
    for (; j < count; ++j) {
        const ushort4 v = hq[(size_t)nbr[j] * FOUT];
        a0 += pw[0][j] * bf2f(v.x);
        a1 += pw[1][j] * bf2f(v.y);
        a2 += pw[2][j] * bf2f(v.z);
    }

    const float tot = a0 / ss0 + a1 / ss1 + a2 / ss2;
    embs[(size_t)urow * FOUT + lane] = tot * (1.f / 3.f) + bias[r * FOUT + lane];
}

// ---- k3: one wave per user node: semantic fusion + classifier + log_softmax.
__global__ __launch_bounds__(64) void k3_fuse(
    const float* __restrict__ h, const float* __restrict__ embs,
    const float* __restrict__ aw1, const float* __restrict__ aw2,
    const float* __restrict__ am, const float* __restrict__ fcw,
    const float* __restrict__ fcb, float* __restrict__ out)
{
    const int n = blockIdx.x;
    const int o = threadIdx.x;

    __shared__ float sh[2][FOUT];
    const float ta0 = embs[((size_t)0 * NUSER + n) * FOUT + o];
    const float ta1 = embs[((size_t)1 * NUSER + n) * FOUT + o];
    sh[0][o] = ta0;
    sh[1][o] = ta1;

    float fa = 0.f;
    const float* hrow = h + (size_t)n * FIN;
    #pragma unroll
    for (int f = 0; f < FIN; ++f) fa += hrow[f] * aw1[f * DD2 + o];
    __syncthreads();

    float e[2];
    #pragma unroll
    for (int r = 0; r < 2; ++r) {
        float t = fa;
        #pragma unroll 8
        for (int j = 0; j < FOUT; ++j) t += sh[r][j] * aw2[j * DD2 + o];
        float q = tanhf(t);
        e[r] = wave_reduce_sum(q * am[o]);
    }
    const float mx = fmaxf(e[0], e[1]);
    float b0 = __expf(e[0] - mx), b1 = __expf(e[1] - mx);
    const float inv = 1.f / (b0 + b1);
    b0 *= inv; b1 *= inv;
    const float fus = b0 * ta0 + b1 * ta1;

    float p0 = ta0 * fcw[(o      ) * 2 + 0] + ta1 * fcw[(64 + o) * 2 + 0] + fus * fcw[(128 + o) * 2 + 0];
    float p1 = ta0 * fcw[(o      ) * 2 + 1] + ta1 * fcw[(64 + o) * 2 + 1] + fus * fcw[(128 + o) * 2 + 1];
    const float lg0 = wave_reduce_sum(p0) + fcb[0];
    const float lg1 = wave_reduce_sum(p1) + fcb[1];

    if (o == 0) {
        const float m2  = fmaxf(lg0, lg1);
        const float lse = m2 + logf(__expf(lg0 - m2) + __expf(lg1 - m2));
        out[(size_t)n * 2 + 0] = lg0 - lse;
        out[(size_t)n * 2 + 1] = lg1 - lse;
    }
}

extern "C" void kernel_launch(void* const* d_in, const int* in_sizes, int n_in,
                              void* d_out, int out_size, void* d_ws, size_t ws_size,
                              hipStream_t stream)
{
    const int*   hadj = (const int*)d_in[0];
    const float* h    = (const float*)d_in[1];
    const float* w    = (const float*)d_in[2];
    const float* asrc = (const float*)d_in[3];
    const float* adst = (const float*)d_in[4];
    const float* bias = (const float*)d_in[5];
    const float* aw1  = (const float*)d_in[6];
    const float* aw2  = (const float*)d_in[7];
    const float* am   = (const float*)d_in[8];
    const float* fcw  = (const float*)d_in[9];
    const float* fcb  = (const float*)d_in[10];
    float* out = (float*)d_out;

    char* ws = (char*)d_ws;
    ushort4* hpq = (ushort4*)ws;                       // RR*NN*64*8 B = 6.29 MB
    ws += (size_t)RR * NN * FOUT * sizeof(ushort4);
    float4* sq = (float4*)ws;                          // RR*NN*16 B
    ws += (size_t)RR * NN * sizeof(float4);
    float4* dq = (float4*)ws;                          // RR*NN*16 B
    ws += (size_t)RR * NN * sizeof(float4);
    float* embs = (float*)ws;                          // RR*NUSER*64*4 B
    ws += (size_t)RR * NUSER * FOUT * sizeof(float);
    int* cnt = (int*)ws;                               // RR*NUSER*4 B
    ws += (size_t)RR * NUSER * sizeof(int);
    int* idx = (int*)ws;                               // RR*NUSER*CAP*4 B = 6.3 MB

    kA_csr <<<RR * NUSER / 4, 256, 0, stream>>>(hadj, cnt, idx);
    k1_proj<<<RR * NN / 2,    128, 0, stream>>>(h, w, asrc, adst, hpq, sq, dq);
    kB_gat <<<RR * NUSER / 4, 256, 0, stream>>>(cnt, idx, hpq, sq, dq, bias, embs);
    k3_fuse<<<NUSER, 64, 0, stream>>>(h, embs, aw1, aw2, am, fcw, fcb, out);
}

// Round 8
// 86.680 us; speedup vs baseline: 1.5701x; 1.0612x over previous
//
#include <hip/hip_runtime.h>
#include <stdint.h>

#define NN 6144
#define NUSER 4096
#define RR 2
#define KK 3
#define FIN 25
#define FOUT 64
#define DD2 64
#define CAP 192

#define SCAN_BLOCKS (RR * NUSER / 4)   // 2048 blocks, 4 row-waves each
#define PROJ_BLOCKS (RR * NN / 4)      // 3072 blocks, 4 row-waves each

typedef int int4v __attribute__((ext_vector_type(4)));

__device__ __forceinline__ float wave_reduce_sum(float v) {
    #pragma unroll
    for (int off = 32; off >= 1; off >>= 1) v += __shfl_xor(v, off);
    return v;
}
__device__ __forceinline__ float wave_reduce_max(float v) {
    #pragma unroll
    for (int off = 32; off >= 1; off >>= 1) v = fmaxf(v, __shfl_xor(v, off));
    return v;
}
__device__ __forceinline__ unsigned short f2bf(float x) {   // RNE
    unsigned int u = __float_as_uint(x);
    unsigned int r = (u + 0x7fffu + ((u >> 16) & 1u)) >> 16;
    return (unsigned short)r;
}
__device__ __forceinline__ float bf2f(unsigned short b) {
    return __uint_as_float(((unsigned int)b) << 16);
}

// ---- kAP: heterogeneous grid. Blocks [0, SCAN_BLOCKS): streaming CSR build
// of user rows (the HBM long pole, dispatched first). Blocks [SCAN_BLOCKS,
// SCAN_BLOCKS+PROJ_BLOCKS): hp projection for ALL nodes — independent work
// that hides under the scan.
__global__ __launch_bounds__(256) void kAP_scan_proj(
    const int* __restrict__ hadj, int* __restrict__ cnt, int* __restrict__ idx,
    const float* __restrict__ h, const float* __restrict__ w,
    const float* __restrict__ asrc, const float* __restrict__ adst,
    ushort4* __restrict__ hpq, float4* __restrict__ sq, float4* __restrict__ dq)
{
    const int wid  = threadIdx.x >> 6;
    const int lane = threadIdx.x & 63;

    if (blockIdx.x < SCAN_BLOCKS) {
        // ================= scan part: one wave per user row =================
        const int urow = blockIdx.x * 4 + wid;        // r*NUSER + n
        const int r    = urow / NUSER;
        const int n    = urow - r * NUSER;
        const int* rowp   = hadj + ((size_t)r * NN + n) * NN;
        int*       rowidx = idx  + (size_t)urow * CAP;
        const unsigned long long below = (1ull << lane) - 1ull;

        int base = 0;
        #pragma unroll 8
        for (int t = 0; t < 24; ++t) {
            const int m0 = t * 256 + lane * 4;
            const int4v v = __builtin_nontemporal_load(
                reinterpret_cast<const int4v*>(rowp + m0));
            const unsigned long long b0 = __ballot(v.x != 0);
            const unsigned long long b1 = __ballot(v.y != 0);
            const unsigned long long b2 = __ballot(v.z != 0);
            const unsigned long long b3 = __ballot(v.w != 0);
            const int n0 = __popcll(b0), n1 = __popcll(b1);
            const int n2 = __popcll(b2), n3 = __popcll(b3);
            const int o0 = base + __popcll(b0 & below);
            const int o1 = base + n0 + __popcll(b1 & below);
            const int o2 = base + n0 + n1 + __popcll(b2 & below);
            const int o3 = base + n0 + n1 + n2 + __popcll(b3 & below);
            if (v.x && o0 < CAP) rowidx[o0] = m0 + 0;
            if (v.y && o1 < CAP) rowidx[o1] = m0 + 1;
            if (v.z && o2 < CAP) rowidx[o2] = m0 + 2;
            if (v.w && o3 < CAP) rowidx[o3] = m0 + 3;
            base += n0 + n1 + n2 + n3;
        }
        if (lane == 0) cnt[urow] = base > CAP ? CAP : base;
    } else {
        // ================= proj part: one wave per (r,n), all n =============
        const int row = (blockIdx.x - SCAN_BLOCKS) * 4 + wid;   // r*NN + n
        const int r   = row / NN;
        const int n   = row % NN;

        const float* hrow = h + (size_t)n * FIN;
        float acc[KK];
        #pragma unroll
        for (int k = 0; k < KK; ++k) {
            const float* wp = w + ((size_t)(r * KK + k) * FIN) * FOUT + lane;
            float a = 0.f;
            #pragma unroll
            for (int f = 0; f < FIN; ++f) a += hrow[f] * wp[f * FOUT];
            acc[k] = a;
        }

        ushort4 pk;
        pk.x = f2bf(acc[0]); pk.y = f2bf(acc[1]); pk.z = f2bf(acc[2]); pk.w = 0;
        hpq[(size_t)row * FOUT + lane] = pk;

        float sv0 = wave_reduce_sum(acc[0] * asrc[(r * KK + 0) * FOUT + lane]);
        float sv1 = wave_reduce_sum(acc[1] * asrc[(r * KK + 1) * FOUT + lane]);
        float sv2 = wave_reduce_sum(acc[2] * asrc[(r * KK + 2) * FOUT + lane]);
        float dv0 = wave_reduce_sum(acc[0] * adst[(r * KK + 0) * FOUT + lane]);
        float dv1 = wave_reduce_sum(acc[1] * adst[(r * KK + 1) * FOUT + lane]);
        float dv2 = wave_reduce_sum(acc[2] * adst[(r * KK + 2) * FOUT + lane]);
        if (lane == 0) {
            sq[row] = make_float4(sv0, sv1, sv2, 0.f);
            dq[row] = make_float4(dv0, dv1, dv2, 0.f);
        }
    }
}

// ---- kB: one wave per user row from CSR; fused 3-head softmax + PV gather.
// 4 waves/block, each wave owns its LDS slice: no barriers.
__global__ __launch_bounds__(256) void kB_gat(
    const int* __restrict__ cnt, const int* __restrict__ idx,
    const ushort4* __restrict__ hpq, const float4* __restrict__ sq,
    const float4* __restrict__ dq, const float* __restrict__ bias,
    float* __restrict__ embs)
{
    const int wid  = threadIdx.x >> 6;
    const int lane = threadIdx.x & 63;
    const int urow = blockIdx.x * 4 + wid;     // r*NUSER + n
    const int r    = urow / NUSER;
    const int n    = urow - r * NUSER;

    __shared__ int   nbr_s[4][CAP];
    __shared__ float pw_s[4][3][CAP];
    int* nbr = nbr_s[wid];
    float (*pw)[CAP] = pw_s[wid];

    const int count = cnt[urow];
    const int* rowidx = idx + (size_t)urow * CAP;

    // logits for all 3 heads (one float4 d-gather per neighbor)
    const float4 sv = sq[(size_t)r * NN + n];
    const float4* dqr = dq + (size_t)r * NN;
    float mx0 = -1e30f, mx1 = -1e30f, mx2 = -1e30f;
    for (int j = lane; j < count; j += 64) {
        const int nb = rowidx[j];
        nbr[j] = nb;
        const float4 dv = dqr[nb];
        float e0 = sv.x + dv.x; e0 = (e0 >= 0.f) ? e0 : 0.2f * e0;
        float e1 = sv.y + dv.y; e1 = (e1 >= 0.f) ? e1 : 0.2f * e1;
        float e2 = sv.z + dv.z; e2 = (e2 >= 0.f) ? e2 : 0.2f * e2;
        pw[0][j] = e0; pw[1][j] = e1; pw[2][j] = e2;
        mx0 = fmaxf(mx0, e0); mx1 = fmaxf(mx1, e1); mx2 = fmaxf(mx2, e2);
    }
    mx0 = wave_reduce_max(mx0);
    mx1 = wave_reduce_max(mx1);
    mx2 = wave_reduce_max(mx2);

    float ss0 = 0.f, ss1 = 0.f, ss2 = 0.f;
    for (int j = lane; j < count; j += 64) {
        float p0 = __expf(pw[0][j] - mx0); pw[0][j] = p0; ss0 += p0;
        float p1 = __expf(pw[1][j] - mx1); pw[1][j] = p1; ss1 += p1;
        float p2 = __expf(pw[2][j] - mx2); pw[2][j] = p2; ss2 += p2;
    }
    ss0 = wave_reduce_sum(ss0);
    ss1 = wave_reduce_sum(ss1);
    ss2 = wave_reduce_sum(ss2);

    // PV gather: one ushort4 (3 heads bf16) coalesced load per neighbor
    const ushort4* hq = hpq + ((size_t)r * NN) * FOUT + lane;
    float a0 = 0.f, a1 = 0.f, a2 = 0.f;
    int j = 0;
    for (; j + 4 <= count; j += 4) {
        #pragma unroll
        for (int u = 0; u < 4; ++u) {
            const ushort4 v = hq[(size_t)nbr[j + u] * FOUT];
            a0 += pw[0][j + u] * bf2f(v.x);
            a1 += pw[1][j + u] * bf2f(v.y);
            a2 += pw[2][j + u] * bf2f(v.z);
        }
    }
    for (; j < count; ++j) {
        const ushort4 v = hq[(size_t)nbr[j] * FOUT];
        a0 += pw[0][j] * bf2f(v.x);
        a1 += pw[1][j] * bf2f(v.y);
        a2 += pw[2][j] * bf2f(v.z);
    }

    const float tot = a0 / ss0 + a1 / ss1 + a2 / ss2;
    embs[(size_t)urow * FOUT + lane] = tot * (1.f / 3.f) + bias[r * FOUT + lane];
}

// ---- k3: one wave per user node: semantic fusion + classifier + log_softmax.
__global__ __launch_bounds__(64) void k3_fuse(
    const float* __restrict__ h, const float* __restrict__ embs,
    const float* __restrict__ aw1, const float* __restrict__ aw2,
    const float* __restrict__ am, const float* __restrict__ fcw,
    const float* __restrict__ fcb, float* __restrict__ out)
{
    const int n = blockIdx.x;
    const int o = threadIdx.x;

    __shared__ float sh[2][FOUT];
    const float ta0 = embs[((size_t)0 * NUSER + n) * FOUT + o];
    const float ta1 = embs[((size_t)1 * NUSER + n) * FOUT + o];
    sh[0][o] = ta0;
    sh[1][o] = ta1;

    float fa = 0.f;
    const float* hrow = h + (size_t)n * FIN;
    #pragma unroll
    for (int f = 0; f < FIN; ++f) fa += hrow[f] * aw1[f * DD2 + o];
    __syncthreads();

    float e[2];
    #pragma unroll
    for (int r = 0; r < 2; ++r) {
        float t = fa;
        #pragma unroll 8
        for (int j = 0; j < FOUT; ++j) t += sh[r][j] * aw2[j * DD2 + o];
        float q = tanhf(t);
        e[r] = wave_reduce_sum(q * am[o]);
    }
    const float mx = fmaxf(e[0], e[1]);
    float b0 = __expf(e[0] - mx), b1 = __expf(e[1] - mx);
    const float inv = 1.f / (b0 + b1);
    b0 *= inv; b1 *= inv;
    const float fus = b0 * ta0 + b1 * ta1;

    float p0 = ta0 * fcw[(o      ) * 2 + 0] + ta1 * fcw[(64 + o) * 2 + 0] + fus * fcw[(128 + o) * 2 + 0];
    float p1 = ta0 * fcw[(o      ) * 2 + 1] + ta1 * fcw[(64 + o) * 2 + 1] + fus * fcw[(128 + o) * 2 + 1];
    const float lg0 = wave_reduce_sum(p0) + fcb[0];
    const float lg1 = wave_reduce_sum(p1) + fcb[1];

    if (o == 0) {
        const float m2  = fmaxf(lg0, lg1);
        const float lse = m2 + logf(__expf(lg0 - m2) + __expf(lg1 - m2));
        out[(size_t)n * 2 + 0] = lg0 - lse;
        out[(size_t)n * 2 + 1] = lg1 - lse;
    }
}

extern "C" void kernel_launch(void* const* d_in, const int* in_sizes, int n_in,
                              void* d_out, int out_size, void* d_ws, size_t ws_size,
                              hipStream_t stream)
{
    const int*   hadj = (const int*)d_in[0];
    const float* h    = (const float*)d_in[1];
    const float* w    = (const float*)d_in[2];
    const float* asrc = (const float*)d_in[3];
    const float* adst = (const float*)d_in[4];
    const float* bias = (const float*)d_in[5];
    const float* aw1  = (const float*)d_in[6];
    const float* aw2  = (const float*)d_in[7];
    const float* am   = (const float*)d_in[8];
    const float* fcw  = (const float*)d_in[9];
    const float* fcb  = (const float*)d_in[10];
    float* out = (float*)d_out;

    char* ws = (char*)d_ws;
    ushort4* hpq = (ushort4*)ws;                       // RR*NN*64*8 B = 6.29 MB
    ws += (size_t)RR * NN * FOUT * sizeof(ushort4);
    float4* sq = (float4*)ws;                          // RR*NN*16 B
    ws += (size_t)RR * NN * sizeof(float4);
    float4* dq = (float4*)ws;                          // RR*NN*16 B
    ws += (size_t)RR * NN * sizeof(float4);
    float* embs = (float*)ws;                          // RR*NUSER*64*4 B
    ws += (size_t)RR * NUSER * FOUT * sizeof(float);
    int* cnt = (int*)ws;                               // RR*NUSER*4 B
    ws += (size_t)RR * NUSER * sizeof(int);
    int* idx = (int*)ws;                               // RR*NUSER*CAP*4 B = 6.3 MB

    kAP_scan_proj<<<SCAN_BLOCKS + PROJ_BLOCKS, 256, 0, stream>>>(
        hadj, cnt, idx, h, w, asrc, adst, hpq, sq, dq);
    kB_gat <<<RR * NUSER / 4, 256, 0, stream>>>(cnt, idx, hpq, sq, dq, bias, embs);
    k3_fuse<<<NUSER, 64, 0, stream>>>(h, embs, aw1, aw2, am, fcw, fcb, out);
}

// Round 9
// 78.044 us; speedup vs baseline: 1.7439x; 1.1106x over previous
//
#include <hip/hip_runtime.h>
#include <stdint.h>

#define NN 6144
#define NUSER 4096
#define RR 2
#define KK 3
#define FIN 25
#define FOUT 64
#define DD2 64
#define CAP 192

#define SCAN_BLOCKS (RR * NUSER / 4)   // 2048 blocks, 4 row-waves each
#define PROJ_BLOCKS (RR * NN / 4)      // 3072 blocks, 4 row-waves each

typedef int int4v __attribute__((ext_vector_type(4)));

__device__ __forceinline__ float wave_reduce_sum(float v) {
    #pragma unroll
    for (int off = 32; off >= 1; off >>= 1) v += __shfl_xor(v, off);
    return v;
}
__device__ __forceinline__ float wave_reduce_max(float v) {
    #pragma unroll
    for (int off = 32; off >= 1; off >>= 1) v = fmaxf(v, __shfl_xor(v, off));
    return v;
}
__device__ __forceinline__ unsigned short f2bf(float x) {   // RNE
    unsigned int u = __float_as_uint(x);
    unsigned int r = (u + 0x7fffu + ((u >> 16) & 1u)) >> 16;
    return (unsigned short)r;
}
__device__ __forceinline__ float bf2f(unsigned short b) {
    return __uint_as_float(((unsigned int)b) << 16);
}

// ---- kAP: heterogeneous grid. Scan blocks first (HBM long pole), proj
// blocks ride along. Plain (non-NT) loads this round.
__global__ __launch_bounds__(256) void kAP_scan_proj(
    const int* __restrict__ hadj, int* __restrict__ cnt, int* __restrict__ idx,
    const float* __restrict__ h, const float* __restrict__ w,
    const float* __restrict__ asrc, const float* __restrict__ adst,
    ushort4* __restrict__ hpq, float4* __restrict__ sq, float4* __restrict__ dq)
{
    const int wid  = threadIdx.x >> 6;
    const int lane = threadIdx.x & 63;

    if (blockIdx.x < SCAN_BLOCKS) {
        // ================= scan part: one wave per user row =================
        const int urow = blockIdx.x * 4 + wid;        // r*NUSER + n
        const int r    = urow / NUSER;
        const int n    = urow - r * NUSER;
        const int* rowp   = hadj + ((size_t)r * NN + n) * NN;
        int*       rowidx = idx  + (size_t)urow * CAP;
        const unsigned long long below = (1ull << lane) - 1ull;

        int base = 0;
        #pragma unroll 8
        for (int t = 0; t < 24; ++t) {
            const int m0 = t * 256 + lane * 4;
            const int4v v = *reinterpret_cast<const int4v*>(rowp + m0);
            const unsigned long long b0 = __ballot(v.x != 0);
            const unsigned long long b1 = __ballot(v.y != 0);
            const unsigned long long b2 = __ballot(v.z != 0);
            const unsigned long long b3 = __ballot(v.w != 0);
            const int n0 = __popcll(b0), n1 = __popcll(b1);
            const int n2 = __popcll(b2), n3 = __popcll(b3);
            const int o0 = base + __popcll(b0 & below);
            const int o1 = base + n0 + __popcll(b1 & below);
            const int o2 = base + n0 + n1 + __popcll(b2 & below);
            const int o3 = base + n0 + n1 + n2 + __popcll(b3 & below);
            if (v.x && o0 < CAP) rowidx[o0] = m0 + 0;
            if (v.y && o1 < CAP) rowidx[o1] = m0 + 1;
            if (v.z && o2 < CAP) rowidx[o2] = m0 + 2;
            if (v.w && o3 < CAP) rowidx[o3] = m0 + 3;
            base += n0 + n1 + n2 + n3;
        }
        if (lane == 0) cnt[urow] = base > CAP ? CAP : base;
    } else {
        // ================= proj part: one wave per (r,n), all n =============
        const int row = (blockIdx.x - SCAN_BLOCKS) * 4 + wid;   // r*NN + n
        const int r   = row / NN;
        const int n   = row % NN;

        const float* hrow = h + (size_t)n * FIN;
        float acc[KK];
        #pragma unroll
        for (int k = 0; k < KK; ++k) {
            const float* wp = w + ((size_t)(r * KK + k) * FIN) * FOUT + lane;
            float a = 0.f;
            #pragma unroll
            for (int f = 0; f < FIN; ++f) a += hrow[f] * wp[f * FOUT];
            acc[k] = a;
        }

        ushort4 pk;
        pk.x = f2bf(acc[0]); pk.y = f2bf(acc[1]); pk.z = f2bf(acc[2]); pk.w = 0;
        hpq[(size_t)row * FOUT + lane] = pk;

        float sv0 = wave_reduce_sum(acc[0] * asrc[(r * KK + 0) * FOUT + lane]);
        float sv1 = wave_reduce_sum(acc[1] * asrc[(r * KK + 1) * FOUT + lane]);
        float sv2 = wave_reduce_sum(acc[2] * asrc[(r * KK + 2) * FOUT + lane]);
        float dv0 = wave_reduce_sum(acc[0] * adst[(r * KK + 0) * FOUT + lane]);
        float dv1 = wave_reduce_sum(acc[1] * adst[(r * KK + 1) * FOUT + lane]);
        float dv2 = wave_reduce_sum(acc[2] * adst[(r * KK + 2) * FOUT + lane]);
        if (lane == 0) {
            sq[row] = make_float4(sv0, sv1, sv2, 0.f);
            dq[row] = make_float4(dv0, dv1, dv2, 0.f);
        }
    }
}

// ---- kBC: one 128-thread block per user node n. Wave r computes GAT row
// (r,n) -> LDS; barrier; wave 0 does semantic fusion + classifier.
__global__ __launch_bounds__(128) void kBC_gat_fuse(
    const int* __restrict__ cnt, const int* __restrict__ idx,
    const ushort4* __restrict__ hpq, const float4* __restrict__ sq,
    const float4* __restrict__ dq, const float* __restrict__ bias,
    const float* __restrict__ h, const float* __restrict__ aw1,
    const float* __restrict__ aw2, const float* __restrict__ am,
    const float* __restrict__ fcw, const float* __restrict__ fcb,
    float* __restrict__ out)
{
    const int n    = blockIdx.x;               // user node
    const int r    = threadIdx.x >> 6;         // wave id = relation
    const int lane = threadIdx.x & 63;
    const int urow = r * NUSER + n;

    __shared__ int   nbr_s[2][CAP];
    __shared__ float pw_s[2][3][CAP];
    __shared__ float emb_s[2][FOUT];
    int* nbr = nbr_s[r];
    float (*pw)[CAP] = pw_s[r];

    const int count = cnt[urow];
    const int* rowidx = idx + (size_t)urow * CAP;

    // ---- logits for all 3 heads (one float4 d-gather per neighbor)
    const float4 sv = sq[(size_t)r * NN + n];
    const float4* dqr = dq + (size_t)r * NN;
    float mx0 = -1e30f, mx1 = -1e30f, mx2 = -1e30f;
    for (int j = lane; j < count; j += 64) {
        const int nb = rowidx[j];
        nbr[j] = nb;
        const float4 dv = dqr[nb];
        float e0 = sv.x + dv.x; e0 = (e0 >= 0.f) ? e0 : 0.2f * e0;
        float e1 = sv.y + dv.y; e1 = (e1 >= 0.f) ? e1 : 0.2f * e1;
        float e2 = sv.z + dv.z; e2 = (e2 >= 0.f) ? e2 : 0.2f * e2;
        pw[0][j] = e0; pw[1][j] = e1; pw[2][j] = e2;
        mx0 = fmaxf(mx0, e0); mx1 = fmaxf(mx1, e1); mx2 = fmaxf(mx2, e2);
    }
    mx0 = wave_reduce_max(mx0);
    mx1 = wave_reduce_max(mx1);
    mx2 = wave_reduce_max(mx2);

    float ss0 = 0.f, ss1 = 0.f, ss2 = 0.f;
    for (int j = lane; j < count; j += 64) {
        float p0 = __expf(pw[0][j] - mx0); pw[0][j] = p0; ss0 += p0;
        float p1 = __expf(pw[1][j] - mx1); pw[1][j] = p1; ss1 += p1;
        float p2 = __expf(pw[2][j] - mx2); pw[2][j] = p2; ss2 += p2;
    }
    ss0 = wave_reduce_sum(ss0);
    ss1 = wave_reduce_sum(ss1);
    ss2 = wave_reduce_sum(ss2);

    // ---- PV gather: one ushort4 (3 heads bf16) coalesced load per neighbor
    const ushort4* hq = hpq + ((size_t)r * NN) * FOUT + lane;
    float a0 = 0.f, a1 = 0.f, a2 = 0.f;
    int j = 0;
    for (; j + 4 <= count; j += 4) {
        #pragma unroll
        for (int u = 0; u < 4; ++u) {
            const ushort4 v = hq[(size_t)nbr[j + u] * FOUT];
            a0 += pw[0][j + u] * bf2f(v.x);
            a1 += pw[1][j + u] * bf2f(v.y);
            a2 += pw[2][j + u] * bf2f(v.z);
        }
    }
    for (; j < count; ++j) {
        const ushort4 v = hq[(size_t)nbr[j] * FOUT];
        a0 += pw[0][j] * bf2f(v.x);
        a1 += pw[1][j] * bf2f(v.y);
        a2 += pw[2][j] * bf2f(v.z);
    }
    emb_s[r][lane] = (a0 / ss0 + a1 / ss1 + a2 / ss2) * (1.f / 3.f)
                   + bias[r * FOUT + lane];
    __syncthreads();

    // ---- semantic fusion + classifier + log_softmax (wave 0 only)
    if (r == 0) {
        const int o = lane;
        const float ta0 = emb_s[0][o];
        const float ta1 = emb_s[1][o];

        float fa = 0.f;
        const float* hrow = h + (size_t)n * FIN;
        #pragma unroll
        for (int f = 0; f < FIN; ++f) fa += hrow[f] * aw1[f * DD2 + o];

        float e[2];
        #pragma unroll
        for (int rr = 0; rr < 2; ++rr) {
            float t = fa;
            #pragma unroll 8
            for (int jj = 0; jj < FOUT; ++jj) t += emb_s[rr][jj] * aw2[jj * DD2 + o];
            float q = tanhf(t);
            e[rr] = wave_reduce_sum(q * am[o]);
        }
        const float mxe = fmaxf(e[0], e[1]);
        float b0 = __expf(e[0] - mxe), b1 = __expf(e[1] - mxe);
        const float inv = 1.f / (b0 + b1);
        b0 *= inv; b1 *= inv;
        const float fus = b0 * ta0 + b1 * ta1;

        float p0 = ta0 * fcw[(o      ) * 2 + 0] + ta1 * fcw[(64 + o) * 2 + 0] + fus * fcw[(128 + o) * 2 + 0];
        float p1 = ta0 * fcw[(o      ) * 2 + 1] + ta1 * fcw[(64 + o) * 2 + 1] + fus * fcw[(128 + o) * 2 + 1];
        const float lg0 = wave_reduce_sum(p0) + fcb[0];
        const float lg1 = wave_reduce_sum(p1) + fcb[1];

        if (o == 0) {
            const float m2  = fmaxf(lg0, lg1);
            const float lse = m2 + logf(__expf(lg0 - m2) + __expf(lg1 - m2));
            out[(size_t)n * 2 + 0] = lg0 - lse;
            out[(size_t)n * 2 + 1] = lg1 - lse;
        }
    }
}

extern "C" void kernel_launch(void* const* d_in, const int* in_sizes, int n_in,
                              void* d_out, int out_size, void* d_ws, size_t ws_size,
                              hipStream_t stream)
{
    const int*   hadj = (const int*)d_in[0];
    const float* h    = (const float*)d_in[1];
    const float* w    = (const float*)d_in[2];
    const float* asrc = (const float*)d_in[3];
    const float* adst = (const float*)d_in[4];
    const float* bias = (const float*)d_in[5];
    const float* aw1  = (const float*)d_in[6];
    const float* aw2  = (const float*)d_in[7];
    const float* am   = (const float*)d_in[8];
    const float* fcw  = (const float*)d_in[9];
    const float* fcb  = (const float*)d_in[10];
    float* out = (float*)d_out;

    char* ws = (char*)d_ws;
    ushort4* hpq = (ushort4*)ws;                       // RR*NN*64*8 B = 6.29 MB
    ws += (size_t)RR * NN * FOUT * sizeof(ushort4);
    float4* sq = (float4*)ws;                          // RR*NN*16 B
    ws += (size_t)RR * NN * sizeof(float4);
    float4* dq = (float4*)ws;                          // RR*NN*16 B
    ws += (size_t)RR * NN * sizeof(float4);
    int* cnt = (int*)ws;                               // RR*NUSER*4 B
    ws += (size_t)RR * NUSER * sizeof(int);
    int* idx = (int*)ws;                               // RR*NUSER*CAP*4 B = 6.3 MB

    kAP_scan_proj<<<SCAN_BLOCKS + PROJ_BLOCKS, 256, 0, stream>>>(
        hadj, cnt, idx, h, w, asrc, adst, hpq, sq, dq);
    kBC_gat_fuse<<<NUSER, 128, 0, stream>>>(
        cnt, idx, hpq, sq, dq, bias, h, aw1, aw2, am, fcw, fcb, out);
}